// Round 13
// baseline (163.997 us; speedup 1.0000x reference)
//
#include <hip/hip_runtime.h>

// VectorQuantizerEMA: ze (32,64,2048) f32, codebook (1024,64) f32
#define B_   32
#define D_   64
#define TP_  2048
#define K_   1024
#define N_   (B_ * TP_)          // 65536 rows
#define BETA_ 0.25f

// ws layout (float units):
//   [0,1024)        : nc2[k] = np-replicated f32 ||c_k||^2 (pairwise-8 sum)
//   [1024]          : commit-loss accumulator (float, atomic)
//   [1025]          : ambiguous-row count (unsigned, atomic)
//   [1088,2112)     : histogram (unsigned, atomic)
//   [2112,18496)    : ambiguous list, u32 entries: (row<<10)|guess
//   [18496,84032)   : pre-swizzled bf16 split-table image, 16 tiles x 16KB.
//                     tile t = codes [t*64, t*64+64); per tile: 4096 ushorts hi,
//                     4096 lo; element (r=code&63, dim j) at ushort
//                     idx r*64 + (j ^ ((r&7)<<3))  [16B-chunk XOR swizzle]
#define WS_SC2   0
#define WS_LOSS  1024
#define WS_CNT   1025
#define WS_HIST  1088
#define WS_LIST  2112
#define WS_TBL   18496
#define CAP_     16384

#define MARGIN_  4e-4f

typedef __attribute__((ext_vector_type(8))) short short8v;   // 8 bf16
typedef __attribute__((ext_vector_type(4))) float float4v;   // C/D frag
#define AS1 __attribute__((address_space(1)))
#define AS3 __attribute__((address_space(3)))

static __device__ __forceinline__ unsigned bf16h(float f) {
    unsigned u = __float_as_uint(f);
    return (u + 0x7FFFu + ((u >> 16) & 1u)) >> 16;   // RNE to bf16
}

// ---------------- init: np ||c||^2, swizzled split tables, zero state --------
__global__ void vq_init(const float* __restrict__ cb, float* __restrict__ ws) {
    int k = blockIdx.x * blockDim.x + threadIdx.x;
    if (k < K_) {
        const float4* c4 = reinterpret_cast<const float4*>(cb + (size_t)k * D_);
        unsigned short* img  = reinterpret_cast<unsigned short*>(ws + WS_TBL);
        unsigned short* tile = img + (size_t)(k >> 6) * 8192;
        const int rr = k & 63;
        float r[8];
#pragma unroll
        for (int i = 0; i < 8; ++i) {
            float4 a = c4[2 * i], b = c4[2 * i + 1];
            float v[8] = {a.x, a.y, a.z, a.w, b.x, b.y, b.z, b.w};
            short8v hi, lo;
#pragma unroll
            for (int j = 0; j < 8; ++j) {
                unsigned hu = bf16h(v[j]);
                float hf = __uint_as_float(hu << 16);
                hi[j] = (short)hu;
                lo[j] = (short)bf16h(v[j] - hf);
                if (i == 0) r[j] = v[j] * v[j]; else r[j] += v[j] * v[j];
            }
            const int off = rr * 64 + ((8 * i) ^ ((rr & 7) << 3));
            *reinterpret_cast<short8v*>(&tile[off])        = hi;
            *reinterpret_cast<short8v*>(&tile[4096 + off]) = lo;
        }
        ws[WS_SC2 + k] = ((r[0] + r[1]) + (r[2] + r[3])) + ((r[4] + r[5]) + (r[6] + r[7]));
        reinterpret_cast<unsigned*>(ws + WS_HIST)[k] = 0u;
        if (k == 0) {
            ws[WS_LOSS] = 0.f;
            reinterpret_cast<unsigned*>(ws)[WS_CNT] = 0u;
        }
    }
}

// ---------------- main: 8-wave K-split MFMA GEMM + merge + outputs -----------
// R9-R12 schedule-invariance at ~90-105us with OccupancyPercent 18.5% (grid
// = 2 waves/SIMD) => latency-bound on wave count. K-split: waves 0-3 scan
// codes [0,512), waves 4-7 scan [512,1024) for the SAME 128 rows; grid 512 x
// 8 waves -> 4 waves/SIMD (2 blocks/CU, 73KB LDS each). Post-loop merge in
// LDS; disjoint code halves so lower-half wins ties = first-index exact.
__global__ __attribute__((amdgpu_flat_work_group_size(512, 512),
                          amdgpu_waves_per_eu(4, 4)))
void vq_main(const float* __restrict__ ze,
             const float* __restrict__ cb,
             float* __restrict__ out,
             float* __restrict__ ws) {
    __shared__ unsigned short lds[2][2][8192] __attribute__((aligned(16)));  // [half][parity]
    __shared__ float sc2_l[K_];
    __shared__ float mbest[128], mbest2[128];
    __shared__ int   midx[128];
    __shared__ int   bidx_sh[128];
    const int tid  = threadIdx.x;
    const int lane = tid & 63;
    const int w    = tid >> 6;         // 0..7
    const int half = w >> 2;           // code half: 0 -> [0,512), 1 -> [512,1024)
    const int wq   = w & 3;            // row-group within block
    const int kg   = lane >> 4;        // k-group 0..3
    const int rc   = lane & 15;        // A-row / B-col selector
    const int n0w  = blockIdx.x * 128 + wq * 32;  // wave's first row

    // ---- A fragments, 2 rowsets: x[row = rs*16+rc][k=s*32+kg*8+e] ----
    short8v ah[2][2], al[2][2];
#pragma unroll
    for (int rs = 0; rs < 2; ++rs) {
        const int nA = n0w + rs * 16 + rc;
        const int bA = nA >> 11, tA = nA & (TP_ - 1);
        const float* zeA = ze + (size_t)bA * (D_ * TP_) + tA;
#pragma unroll
        for (int s = 0; s < 2; ++s) {
#pragma unroll
            for (int e = 0; e < 8; ++e) {
                float xv = zeA[(size_t)(s * 32 + kg * 8 + e) * TP_];
                unsigned hu = bf16h(xv);
                float hf = __uint_as_float(hu << 16);
                ah[rs][s][e] = (short)hu;
                al[rs][s][e] = (short)bf16h(xv - hf);
            }
        }
    }

    // stage sc2 (4KB) into LDS: waves 0-3, 1KB each
    if (w < 4) {
        const float* g = ws + WS_SC2 + w * 256 + lane * 4;
        __builtin_amdgcn_global_load_lds((const AS1 unsigned int*)g,
                                         (AS3 unsigned int*)&sc2_l[w * 256], 16, 0, 0);
    }
    const unsigned short* img = reinterpret_cast<const unsigned short*>(ws + WS_TBL);

    float best[2][4], best2[2][4];
    int   bidx[2][4];
#pragma unroll
    for (int rs = 0; rs < 2; ++rs)
#pragma unroll
        for (int r = 0; r < 4; ++r) {
            best[rs][r] = 3.4e38f; best2[rs][r] = 3.4e38f; bidx[rs][r] = 0;
        }

    // stage tile t (16KB) into lds[t>>3][t&1]: 512 thr x 2 x 16B, linear dest
#define STAGE(t) do {                                                             \
        const unsigned short* _g = img + (size_t)(t) * 8192;                      \
        unsigned short* _l = lds[(t) >> 3][(t) & 1];                              \
        _Pragma("unroll")                                                         \
        for (int _c = 0; _c < 2; ++_c) {                                          \
            __builtin_amdgcn_global_load_lds(                                     \
                (const AS1 unsigned int*)(_g + _c * 4096 + (size_t)tid * 8),      \
                (AS3 unsigned int*)(_l + _c * 4096 + w * 512), 16, 0, 0);         \
        }                                                                         \
    } while (0)

#define SUBTILE(ss, sub) do {                                                     \
        const int r_  = (sub) * 16 + rc;                                          \
        const int cx0 = (kg * 8) ^ ((r_ & 7) << 3);                               \
        const int cx1 = (32 + kg * 8) ^ ((r_ & 7) << 3);                          \
        const unsigned short* bp = &lds[half][(ss) & 1][r_ * 64];                 \
        short8v bh0 = *reinterpret_cast<const short8v*>(bp + cx0);                \
        short8v bh1 = *reinterpret_cast<const short8v*>(bp + cx1);                \
        short8v bl0 = *reinterpret_cast<const short8v*>(bp + 4096 + cx0);         \
        short8v bl1 = *reinterpret_cast<const short8v*>(bp + 4096 + cx1);         \
        const int code = half * 512 + (ss) * 64 + (sub) * 16 + rc;                \
        const float s2 = sc2_l[code];                                             \
        _Pragma("unroll")                                                         \
        for (int rs = 0; rs < 2; ++rs) {                                          \
            float4v acc = {0.f, 0.f, 0.f, 0.f};                                   \
            acc = __builtin_amdgcn_mfma_f32_16x16x32_bf16(ah[rs][0], bh0, acc, 0, 0, 0); \
            acc = __builtin_amdgcn_mfma_f32_16x16x32_bf16(ah[rs][1], bh1, acc, 0, 0, 0); \
            acc = __builtin_amdgcn_mfma_f32_16x16x32_bf16(ah[rs][0], bl0, acc, 0, 0, 0); \
            acc = __builtin_amdgcn_mfma_f32_16x16x32_bf16(ah[rs][1], bl1, acc, 0, 0, 0); \
            acc = __builtin_amdgcn_mfma_f32_16x16x32_bf16(al[rs][0], bh0, acc, 0, 0, 0); \
            acc = __builtin_amdgcn_mfma_f32_16x16x32_bf16(al[rs][1], bh1, acc, 0, 0, 0); \
            _Pragma("unroll")                                                     \
            for (int r = 0; r < 4; ++r) {                                         \
                float v = fmaf(-2.f, acc[r], s2);                                 \
                if (v < best[rs][r]) { best2[rs][r] = best[rs][r];                \
                    best[rs][r] = v; bidx[rs][r] = code; }                        \
                else if (v < best2[rs][r]) best2[rs][r] = v;                      \
            }                                                                     \
        }                                                                         \
    } while (0)

    STAGE(0); STAGE(8);                // step-0 tiles for both halves
    for (int ss = 0; ss < 8; ++ss) {
        asm volatile("s_waitcnt vmcnt(0)" ::: "memory");  // stage ss done (issued a full step ago)
        __builtin_amdgcn_sched_barrier(0);
        __builtin_amdgcn_s_barrier();                     // all waves done with parity ss^1
        if (ss < 7) { STAGE(ss + 1); STAGE(9 + ss); }     // prefetch both halves
        __builtin_amdgcn_sched_barrier(0);
        SUBTILE(ss, 0);
        SUBTILE(ss, 1);
        SUBTILE(ss, 2);
        SUBTILE(ss, 3);
    }
#undef STAGE
#undef SUBTILE

    // reduce (best,best2,idx) across the 16 cols (low 4 lane bits)
#pragma unroll
    for (int rs = 0; rs < 2; ++rs)
#pragma unroll
    for (int r = 0; r < 4; ++r) {
        unsigned fu = __float_as_uint(best[rs][r]);
        fu = (fu & 0x80000000u) ? ~fu : (fu | 0x80000000u);   // order-preserving
        unsigned long long pk = ((unsigned long long)fu << 32) | (unsigned)bidx[rs][r];
        float bf = best[rs][r], b2 = best2[rs][r];
#pragma unroll
        for (int m = 1; m <= 8; m <<= 1) {
            unsigned long long po = __shfl_xor(pk, m, 64);
            float bo  = __shfl_xor(bf, m, 64);
            float b2o = __shfl_xor(b2, m, 64);
            b2 = fminf(fminf(b2, b2o), fmaxf(bf, bo));
            bf = fminf(bf, bo);
            if (po < pk) pk = po;
        }
        best[rs][r] = bf; best2[rs][r] = b2; bidx[rs][r] = (int)(pk & 0x3FFull);
    }

    // K-split merge: half-1 posts, half-0 combines (lower half wins ties =
    // first-index, since all half-0 codes < half-1 codes)
    if (half == 1 && rc == 0) {
#pragma unroll
        for (int rs = 0; rs < 2; ++rs)
#pragma unroll
        for (int r = 0; r < 4; ++r) {
            const int rowb = wq * 32 + rs * 16 + kg * 4 + r;
            mbest[rowb]  = best[rs][r];
            mbest2[rowb] = best2[rs][r];
            midx[rowb]   = bidx[rs][r];
        }
    }
    __syncthreads();

    if (half == 0 && rc == 0) {
        unsigned* gh = reinterpret_cast<unsigned*>(ws + WS_HIST);
#pragma unroll
        for (int rs = 0; rs < 2; ++rs)
#pragma unroll
        for (int r = 0; r < 4; ++r) {
            const int rowb = wq * 32 + rs * 16 + kg * 4 + r;
            const int n    = blockIdx.x * 128 + rowb;
            float bA = best[rs][r],  b2A = best2[rs][r];
            float bB = mbest[rowb],  b2B = mbest2[rowb];
            int   iM = (bB < bA) ? midx[rowb] : bidx[rs][r];
            float bM = fminf(bA, bB);
            float b2M = fminf(fminf(b2A, b2B), fmaxf(bA, bB));
            out[(size_t)N_ * D_ + n] = (float)iM;
            atomicAdd(&gh[iM], 1u);
            if (b2M - bM < MARGIN_) {
                unsigned slot = atomicAdd(reinterpret_cast<unsigned*>(ws) + WS_CNT, 1u);
                if (slot < CAP_)
                    reinterpret_cast<unsigned*>(ws + WS_LIST)[slot] =
                        ((unsigned)n << 10) | (unsigned)iM;
            }
            bidx_sh[rowb] = iM;
        }
    }
    __syncthreads();

    // ---- phase2: zq gather-write + commit loss (128 rows x 4 dim-chunks) ----
    const int row   = tid & 127;
    const int chunk = tid >> 7;                    // dims [chunk*16, +16)
    const int n2 = blockIdx.x * 128 + row;
    const int b2i = n2 >> 11, t2 = n2 & (TP_ - 1);
    const int k2 = bidx_sh[row];
    const float* zer = ze + (size_t)b2i * (D_ * TP_) + t2;
    float* outr = out + (size_t)b2i * (D_ * TP_) + t2;
    const float4* cr4 = reinterpret_cast<const float4*>(cb + (size_t)k2 * D_ + chunk * 16);
    float lsum = 0.f;
#pragma unroll
    for (int q4 = 0; q4 < 4; ++q4) {
        float4 q = cr4[q4];
        float qv[4] = {q.x, q.y, q.z, q.w};
#pragma unroll
        for (int c = 0; c < 4; ++c) {
            const int d = chunk * 16 + q4 * 4 + c;
            outr[(size_t)d * TP_] = qv[c];        // ze + (zq - ze) == zq
            float diff = zer[(size_t)d * TP_] - qv[c];
            lsum = fmaf(diff, diff, lsum);
        }
    }
#pragma unroll
    for (int m = 32; m >= 1; m >>= 1) lsum += __shfl_xor(lsum, m, 64);
    if (lane == 0) atomicAdd(ws + WS_LOSS, lsum);
}

// ---------------- fixup: replicate ref grid argmin for ambiguous rows -------
// x in LDS read as float4 (pipelined ds_read_b128); 4-way f64 accumulators;
// per-code asm memory clobber defeats the LICM hoist that caused spills.
__global__ __attribute__((amdgpu_flat_work_group_size(256, 256)))
void vq_fix(const float* __restrict__ ze,
            const float* __restrict__ cb,
            float* __restrict__ out,
            float* __restrict__ ws) {
    __shared__ float xls[4][64];
    const int lane = threadIdx.x & 63;
    const int wl   = threadIdx.x >> 6;
    const unsigned w = blockIdx.x * 4 + wl;                  // wave id, 256 total
    unsigned cnt = reinterpret_cast<const unsigned*>(ws)[WS_CNT];
    if (cnt > CAP_) cnt = CAP_;
    const unsigned* list = reinterpret_cast<const unsigned*>(ws + WS_LIST);
    const float* sc2 = ws + WS_SC2;
    unsigned* gh = reinterpret_cast<unsigned*>(ws + WS_HIST);

    for (unsigned i = w; i < cnt; i += 256) {
        unsigned e = list[i];
        const int n     = (int)(e >> 10);
        const int guess = (int)(e & 1023u);
        const int b  = n >> 11;
        const int tp = n & (TP_ - 1);
        const float* zp = ze + (size_t)b * D_ * TP_ + tp;    // wave-uniform

        xls[wl][lane] = zp[(size_t)lane * TP_];
        asm volatile("s_waitcnt lgkmcnt(0)" ::: "memory");

        // np pairwise-8 ||x||^2 (bit-exact np.sum(x*x, axis=1))
        float r[8];
#pragma unroll
        for (int j = 0; j < 8; ++j) { float v = xls[wl][j]; r[j] = v * v; }
#pragma unroll
        for (int ii = 1; ii < 8; ++ii)
#pragma unroll
            for (int j = 0; j < 8; ++j) { float v = xls[wl][8 * ii + j]; r[j] += v * v; }
        float nx2 = ((r[0] + r[1]) + (r[2] + r[3])) + ((r[4] + r[5]) + (r[6] + r[7]));

        const float4* x4 = reinterpret_cast<const float4*>(xls[wl]);
        unsigned long long m = ~0ull;
        const int kbase = lane * 16;
#pragma unroll 1
        for (int kk = 0; kk < 16; ++kk) {
            const int k = kbase + kk;
            const float4* cp4 = reinterpret_cast<const float4*>(cb + (size_t)k * D_);
            asm volatile("" ::: "memory");       // force x4 re-reads (no 64-reg hoist)
            double a0 = 0.0, a1 = 0.0, a2 = 0.0, a3 = 0.0;
#pragma unroll
            for (int j4 = 0; j4 < 16; ++j4) {
                float4 xv = x4[j4];
                float4 cv = cp4[j4];
                a0 = fma((double)xv.x, (double)cv.x, a0);
                a1 = fma((double)xv.y, (double)cv.y, a1);
                a2 = fma((double)xv.z, (double)cv.z, a2);
                a3 = fma((double)xv.w, (double)cv.w, a3);
            }
            float dotf = (float)((a0 + a1) + (a2 + a3));
            float A    = nx2 + sc2[k];
            float dist = A - 2.0f * dotf;
            unsigned long long pk =
                ((unsigned long long)__float_as_uint(dist) << 32) | (unsigned)k;
            if (pk < m) m = pk;
        }
#pragma unroll
        for (int s = 32; s >= 1; s >>= 1) {
            unsigned long long o = __shfl_xor(m, s, 64);
            if (o < m) m = o;
        }
        const int gk = (int)(m & 0xFFFFFFFFull);

        if (gk != guess) {
            out[(size_t)b * D_ * TP_ + (size_t)lane * TP_ + tp] = cb[(size_t)gk * D_ + lane];
            float xl = xls[wl][lane];
            float dn = xl - cb[(size_t)gk * D_ + lane];
            float dq = xl - cb[(size_t)guess * D_ + lane];
            float t  = dn * dn - dq * dq;
#pragma unroll
            for (int s = 32; s >= 1; s >>= 1) t += __shfl_xor(t, s, 64);
            if (lane == 0) {
                atomicAdd(ws + WS_LOSS, t);
                out[(size_t)N_ * D_ + n] = (float)gk;
                atomicSub(&gh[guess], 1u);
                atomicAdd(&gh[gk], 1u);
            }
        }
    }
}

// ---------------- finalize: scalars ----------------
__global__ void vq_fin(const float* __restrict__ ws, float* __restrict__ out) {
    __shared__ double red[K_];
    const int t = threadIdx.x;
    const unsigned* gh = reinterpret_cast<const unsigned*>(ws + WS_HIST);
    double p = (double)gh[t] * (1.0 / (double)N_);
    red[t] = -p * log(p + 1e-10);
    __syncthreads();
    for (int s = 512; s > 0; s >>= 1) {
        if (t < s) red[t] += red[t + s];
        __syncthreads();
    }
    if (t == 0) {
        out[(size_t)N_ * D_ + N_]     = BETA_ * ws[WS_LOSS] * (1.0f / (float)(N_ * D_));
        out[(size_t)N_ * D_ + N_ + 1] = (float)exp(red[0]);
    }
}

extern "C" void kernel_launch(void* const* d_in, const int* in_sizes, int n_in,
                              void* d_out, int out_size, void* d_ws, size_t ws_size,
                              hipStream_t stream) {
    const float* ze = (const float*)d_in[0];
    const float* cb = (const float*)d_in[1];
    float* out = (float*)d_out;
    float* ws  = (float*)d_ws;

    vq_init<<<dim3(16), dim3(64), 0, stream>>>(cb, ws);
    vq_main<<<dim3(N_ / 128), dim3(512), 0, stream>>>(ze, cb, out, ws);
    vq_fix<<<dim3(64), dim3(256), 0, stream>>>(ze, cb, out, ws);
    vq_fin<<<dim3(1), dim3(K_), 0, stream>>>(ws, out);
}

// Round 14
// 128.847 us; speedup vs baseline: 1.2728x; 1.2728x over previous
//
#include <hip/hip_runtime.h>

// VectorQuantizerEMA: ze (32,64,2048) f32, codebook (1024,64) f32
#define B_   32
#define D_   64
#define TP_  2048
#define K_   1024
#define N_   (B_ * TP_)          // 65536 rows
#define BETA_ 0.25f

// ws layout (float units):
//   [0,1024)        : nc2[k] = np-replicated f32 ||c_k||^2 (pairwise-8 sum)
//   [1024]          : commit-loss accumulator (float, atomic)
//   [1025]          : ambiguous-row count (unsigned, atomic)
//   [1088,2112)     : histogram (unsigned, atomic)
//   [2112,18496)    : ambiguous list, u32 entries: (row<<10)|guess
//   [18496,84032)   : pre-swizzled bf16 split-table image, 16 tiles x 16KB.
//                     tile t64 = codes [t64*64,+64); per tile: 4096 ushorts hi,
//                     4096 lo; element (r=code&63, dim j) at ushort
//                     idx r*64 + (j ^ ((r&7)<<3))  [16B-chunk XOR swizzle]
#define WS_SC2   0
#define WS_LOSS  1024
#define WS_CNT   1025
#define WS_HIST  1088
#define WS_LIST  2112
#define WS_TBL   18496
#define CAP_     16384

// 4-term split dot: our err ~1.5e-6; ref grid err ~8e-6 -> need >2e-5; 6e-5
// gives 3x headroom. Flagged rows ~= 8/unit * 6e-5 * 65536 ~= 30.
#define MARGIN_  6e-5f

typedef __attribute__((ext_vector_type(8))) short short8v;   // 8 bf16
typedef __attribute__((ext_vector_type(4))) float float4v;   // C/D frag
#define AS1 __attribute__((address_space(1)))
#define AS3 __attribute__((address_space(3)))

static __device__ __forceinline__ unsigned bf16h(float f) {
    unsigned u = __float_as_uint(f);
    return (u + 0x7FFFu + ((u >> 16) & 1u)) >> 16;   // RNE to bf16
}

// ---------------- init: np ||c||^2, swizzled split tables, zero state --------
__global__ void vq_init(const float* __restrict__ cb, float* __restrict__ ws) {
    int k = blockIdx.x * blockDim.x + threadIdx.x;
    if (k < K_) {
        const float4* c4 = reinterpret_cast<const float4*>(cb + (size_t)k * D_);
        unsigned short* img  = reinterpret_cast<unsigned short*>(ws + WS_TBL);
        unsigned short* tile = img + (size_t)(k >> 6) * 8192;
        const int rr = k & 63;
        float r[8];
#pragma unroll
        for (int i = 0; i < 8; ++i) {
            float4 a = c4[2 * i], b = c4[2 * i + 1];
            float v[8] = {a.x, a.y, a.z, a.w, b.x, b.y, b.z, b.w};
            short8v hi, lo;
#pragma unroll
            for (int j = 0; j < 8; ++j) {
                unsigned hu = bf16h(v[j]);
                float hf = __uint_as_float(hu << 16);
                hi[j] = (short)hu;
                lo[j] = (short)bf16h(v[j] - hf);
                if (i == 0) r[j] = v[j] * v[j]; else r[j] += v[j] * v[j];
            }
            const int off = rr * 64 + ((8 * i) ^ ((rr & 7) << 3));
            *reinterpret_cast<short8v*>(&tile[off])        = hi;
            *reinterpret_cast<short8v*>(&tile[4096 + off]) = lo;
        }
        ws[WS_SC2 + k] = ((r[0] + r[1]) + (r[2] + r[3])) + ((r[4] + r[5]) + (r[6] + r[7]));
        reinterpret_cast<unsigned*>(ws + WS_HIST)[k] = 0u;
        if (k == 0) {
            ws[WS_LOSS] = 0.f;
            reinterpret_cast<unsigned*>(ws)[WS_CNT] = 0u;
        }
    }
}

// ---------------- main: barrier-free wave-private MFMA GEMM ------------------
// R9-R13: every block-barrier schedule landed 90-106us with all pipes <26%
// busy (convoy: waves burst LDS together, then MFMA together). Fix: vmcnt is
// PER-WAVE, so give each wave a private 2x8KB LDS ring staged by
// global_load_lds with per-wave vmcnt(8) counting - zero barriers in the
// K-loop, waves free-run, pipes interleave. 4-term split dot (8 MFMA/subtile)
// shrinks MARGIN 4e-4 -> 6e-5 (fixup rows ~200 -> ~30).
__global__ __attribute__((amdgpu_flat_work_group_size(256, 256),
                          amdgpu_waves_per_eu(2, 2)))
void vq_main(const float* __restrict__ ze,
             const float* __restrict__ cb,
             float* __restrict__ out,
             float* __restrict__ ws) {
    __shared__ unsigned short lds[4][2][4096] __attribute__((aligned(16)));  // [wave][parity]
    __shared__ float sc2_l[K_];
    __shared__ int bidx_sh[128];
    const int tid  = threadIdx.x;
    const int lane = tid & 63;
    const int w    = tid >> 6;         // 0..3
    const int kg   = lane >> 4;        // k-group 0..3
    const int rc   = lane & 15;        // A-row / B-col selector
    const int n0w  = blockIdx.x * 128 + w * 32;  // wave's first row

    // ---- A fragments, 2 rowsets: x[row = rs*16+rc][k=s*32+kg*8+e] ----
    short8v ah[2][2], al[2][2];
#pragma unroll
    for (int rs = 0; rs < 2; ++rs) {
        const int nA = n0w + rs * 16 + rc;
        const int bA = nA >> 11, tA = nA & (TP_ - 1);
        const float* zeA = ze + (size_t)bA * (D_ * TP_) + tA;
#pragma unroll
        for (int s = 0; s < 2; ++s) {
#pragma unroll
            for (int e = 0; e < 8; ++e) {
                float xv = zeA[(size_t)(s * 32 + kg * 8 + e) * TP_];
                unsigned hu = bf16h(xv);
                float hf = __uint_as_float(hu << 16);
                ah[rs][s][e] = (short)hu;
                al[rs][s][e] = (short)bf16h(xv - hf);
            }
        }
    }

    // stage sc2 (4KB) into LDS
    {
        const float* g = ws + WS_SC2 + w * 256 + lane * 4;
        __builtin_amdgcn_global_load_lds((const AS1 unsigned int*)g,
                                         (AS3 unsigned int*)&sc2_l[w * 256], 16, 0, 0);
    }
    const unsigned short* img = reinterpret_cast<const unsigned short*>(ws + WS_TBL);

    float best[2][4], best2[2][4];
    int   bidx[2][4];
#pragma unroll
    for (int rs = 0; rs < 2; ++rs)
#pragma unroll
        for (int r = 0; r < 4; ++r) {
            best[rs][r] = 3.4e38f; best2[rs][r] = 3.4e38f; bidx[rs][r] = 0;
        }

    // wave-private stage of 32-code tile t: 8 x global_load_lds (16B/lane)
#define STAGE(t) do {                                                             \
        const unsigned short* _src = img + (size_t)((t) >> 1) * 8192              \
                                         + (size_t)((t) & 1) * 2048;              \
        unsigned short* _dh = &lds[w][(t) & 1][0];                                \
        unsigned short* _dl = &lds[w][(t) & 1][2048];                             \
        _Pragma("unroll")                                                         \
        for (int _c = 0; _c < 4; ++_c) {                                          \
            __builtin_amdgcn_global_load_lds(                                     \
                (const AS1 unsigned int*)(_src + _c * 512 + lane * 8),            \
                (AS3 unsigned int*)(_dh + _c * 512), 16, 0, 0);                   \
            __builtin_amdgcn_global_load_lds(                                     \
                (const AS1 unsigned int*)(_src + 4096 + _c * 512 + lane * 8),     \
                (AS3 unsigned int*)(_dl + _c * 512), 16, 0, 0);                   \
        }                                                                         \
    } while (0)

    // tile t: 8 ds_read_b128, re-stage t+2 after lgkm drain, 32 MFMA, argmin
#define TILE(t) do {                                                              \
        const unsigned short* _b = lds[w][(t) & 1];                               \
        short8v bh0[2], bh1[2], bl0[2], bl1[2];                                   \
        _Pragma("unroll")                                                         \
        for (int _s = 0; _s < 2; ++_s) {                                          \
            const int r_  = _s * 16 + rc;                                         \
            const int cx0 = (kg * 8) ^ ((r_ & 7) << 3);                           \
            const int cx1 = (32 + kg * 8) ^ ((r_ & 7) << 3);                      \
            bh0[_s] = *reinterpret_cast<const short8v*>(_b + r_ * 64 + cx0);      \
            bh1[_s] = *reinterpret_cast<const short8v*>(_b + r_ * 64 + cx1);      \
            bl0[_s] = *reinterpret_cast<const short8v*>(_b + 2048 + r_ * 64 + cx0); \
            bl1[_s] = *reinterpret_cast<const short8v*>(_b + 2048 + r_ * 64 + cx1); \
        }                                                                         \
        asm volatile("s_waitcnt lgkmcnt(0)" ::: "memory");                        \
        __builtin_amdgcn_sched_barrier(0);                                        \
        if ((t) < 30) STAGE((t) + 2);                                             \
        _Pragma("unroll")                                                         \
        for (int _s = 0; _s < 2; ++_s) {                                          \
            const int code = (t) * 32 + _s * 16 + rc;                             \
            const float s2 = sc2_l[code];                                         \
            _Pragma("unroll")                                                     \
            for (int rs = 0; rs < 2; ++rs) {                                      \
                float4v acc = {0.f, 0.f, 0.f, 0.f};                               \
                acc = __builtin_amdgcn_mfma_f32_16x16x32_bf16(ah[rs][0], bh0[_s], acc, 0, 0, 0); \
                acc = __builtin_amdgcn_mfma_f32_16x16x32_bf16(ah[rs][1], bh1[_s], acc, 0, 0, 0); \
                acc = __builtin_amdgcn_mfma_f32_16x16x32_bf16(ah[rs][0], bl0[_s], acc, 0, 0, 0); \
                acc = __builtin_amdgcn_mfma_f32_16x16x32_bf16(ah[rs][1], bl1[_s], acc, 0, 0, 0); \
                acc = __builtin_amdgcn_mfma_f32_16x16x32_bf16(al[rs][0], bh0[_s], acc, 0, 0, 0); \
                acc = __builtin_amdgcn_mfma_f32_16x16x32_bf16(al[rs][1], bh1[_s], acc, 0, 0, 0); \
                acc = __builtin_amdgcn_mfma_f32_16x16x32_bf16(al[rs][0], bl0[_s], acc, 0, 0, 0); \
                acc = __builtin_amdgcn_mfma_f32_16x16x32_bf16(al[rs][1], bl1[_s], acc, 0, 0, 0); \
                _Pragma("unroll")                                                 \
                for (int r = 0; r < 4; ++r) {                                     \
                    float v = fmaf(-2.f, acc[r], s2);                             \
                    if (v < best[rs][r]) { best2[rs][r] = best[rs][r];            \
                        best[rs][r] = v; bidx[rs][r] = code; }                    \
                    else if (v < best2[rs][r]) best2[rs][r] = v;                  \
                }                                                                 \
            }                                                                     \
        }                                                                         \
    } while (0)

    __syncthreads();                  // drain A-loads + sc2 stage; publish sc2_l

    STAGE(0); STAGE(1);               // 16 outstanding
    for (int t = 0; t < 31; ++t) {
        asm volatile("s_waitcnt vmcnt(8)" ::: "memory");  // retire stage t (t+1 stays in flight)
        __builtin_amdgcn_sched_barrier(0);
        TILE(t);
    }
    asm volatile("s_waitcnt vmcnt(0)" ::: "memory");      // retire stage 31
    __builtin_amdgcn_sched_barrier(0);
    TILE(31);
#undef STAGE
#undef TILE

    // reduce (best,best2,idx) across the 16 cols (low 4 lane bits)
#pragma unroll
    for (int rs = 0; rs < 2; ++rs)
#pragma unroll
    for (int r = 0; r < 4; ++r) {
        unsigned fu = __float_as_uint(best[rs][r]);
        fu = (fu & 0x80000000u) ? ~fu : (fu | 0x80000000u);   // order-preserving
        unsigned long long pk = ((unsigned long long)fu << 32) | (unsigned)bidx[rs][r];
        float bf = best[rs][r], b2 = best2[rs][r];
#pragma unroll
        for (int m = 1; m <= 8; m <<= 1) {
            unsigned long long po = __shfl_xor(pk, m, 64);
            float bo  = __shfl_xor(bf, m, 64);
            float b2o = __shfl_xor(b2, m, 64);
            b2 = fminf(fminf(b2, b2o), fmaxf(bf, bo));
            bf = fminf(bf, bo);
            if (po < pk) pk = po;
        }
        best[rs][r] = bf; best2[rs][r] = b2; bidx[rs][r] = (int)(pk & 0x3FFull);
    }

    if (rc == 0) {
        unsigned* gh = reinterpret_cast<unsigned*>(ws + WS_HIST);
#pragma unroll
        for (int rs = 0; rs < 2; ++rs)
#pragma unroll
        for (int r = 0; r < 4; ++r) {
            const int row = rs * 16 + kg * 4 + r;    // row within wave tile
            const int n   = n0w + row;
            const int k   = bidx[rs][r];
            out[(size_t)N_ * D_ + n] = (float)k;
            atomicAdd(&gh[k], 1u);
            if (best2[rs][r] - best[rs][r] < MARGIN_) {
                unsigned slot = atomicAdd(reinterpret_cast<unsigned*>(ws) + WS_CNT, 1u);
                if (slot < CAP_)
                    reinterpret_cast<unsigned*>(ws + WS_LIST)[slot] =
                        ((unsigned)n << 10) | (unsigned)k;
            }
            bidx_sh[w * 32 + row] = k;
        }
    }
    __syncthreads();

    // ---- phase2: zq gather-write + commit loss (128 rows x 2 dim-chunks) ----
    const int row   = tid & 127;
    const int chunk = tid >> 7;                    // dims [chunk*32, +32)
    const int n2 = blockIdx.x * 128 + row;
    const int b2i = n2 >> 11, t2 = n2 & (TP_ - 1);
    const int k2 = bidx_sh[row];
    const float* zer = ze + (size_t)b2i * (D_ * TP_) + t2;
    float* outr = out + (size_t)b2i * (D_ * TP_) + t2;
    const float4* cr4 = reinterpret_cast<const float4*>(cb + (size_t)k2 * D_ + chunk * 32);
    float lsum = 0.f;
#pragma unroll
    for (int q4 = 0; q4 < 8; ++q4) {
        float4 q = cr4[q4];
        float qv[4] = {q.x, q.y, q.z, q.w};
#pragma unroll
        for (int c = 0; c < 4; ++c) {
            const int d = chunk * 32 + q4 * 4 + c;
            outr[(size_t)d * TP_] = qv[c];        // ze + (zq - ze) == zq
            float diff = zer[(size_t)d * TP_] - qv[c];
            lsum = fmaf(diff, diff, lsum);
        }
    }
#pragma unroll
    for (int m = 32; m >= 1; m >>= 1) lsum += __shfl_xor(lsum, m, 64);
    if (lane == 0) atomicAdd(ws + WS_LOSS, lsum);
}

// ---------------- fixup: ref-grid argmin, one row per block ------------------
// 4 codes/thread x 256 threads; x shared in LDS; per-thread f64 work = 256
// FMA with ~30 live regs (structurally spill-proof, unlike R8-R13 variants).
__global__ __attribute__((amdgpu_flat_work_group_size(256, 256)))
void vq_fix(const float* __restrict__ ze,
            const float* __restrict__ cb,
            float* __restrict__ out,
            float* __restrict__ ws) {
    __shared__ float xls[64] __attribute__((aligned(16)));
    __shared__ unsigned long long wmin[4];
    __shared__ int gks;
    const int tid  = threadIdx.x;
    const int lane = tid & 63;
    const int wl   = tid >> 6;
    unsigned cnt = reinterpret_cast<const unsigned*>(ws)[WS_CNT];
    if (cnt > CAP_) cnt = CAP_;
    const unsigned* list = reinterpret_cast<const unsigned*>(ws + WS_LIST);
    const float* sc2 = ws + WS_SC2;
    unsigned* gh = reinterpret_cast<unsigned*>(ws + WS_HIST);

    for (unsigned i = blockIdx.x; i < cnt; i += 64) {
        unsigned e = list[i];
        const int n     = (int)(e >> 10);
        const int guess = (int)(e & 1023u);
        const int b  = n >> 11;
        const int tp = n & (TP_ - 1);
        const float* zp = ze + (size_t)b * D_ * TP_ + tp;

        if (tid < 64) xls[tid] = zp[(size_t)tid * TP_];
        __syncthreads();

        // np pairwise-8 ||x||^2 (bit-exact np.sum(x*x, axis=1)); redundant/thread
        float r[8];
#pragma unroll
        for (int j = 0; j < 8; ++j) { float v = xls[j]; r[j] = v * v; }
#pragma unroll
        for (int ii = 1; ii < 8; ++ii)
#pragma unroll
            for (int j = 0; j < 8; ++j) { float v = xls[8 * ii + j]; r[j] += v * v; }
        float nx2 = ((r[0] + r[1]) + (r[2] + r[3])) + ((r[4] + r[5]) + (r[6] + r[7]));

        const float4* x4 = reinterpret_cast<const float4*>(xls);
        unsigned long long m = ~0ull;
#pragma unroll
        for (int kk = 0; kk < 4; ++kk) {
            const int k = tid * 4 + kk;
            const float4* cp4 = reinterpret_cast<const float4*>(cb + (size_t)k * D_);
            double a0 = 0.0, a1 = 0.0, a2 = 0.0, a3 = 0.0;
#pragma unroll
            for (int j4 = 0; j4 < 16; ++j4) {
                float4 xv = x4[j4];
                float4 cv = cp4[j4];
                a0 = fma((double)xv.x, (double)cv.x, a0);
                a1 = fma((double)xv.y, (double)cv.y, a1);
                a2 = fma((double)xv.z, (double)cv.z, a2);
                a3 = fma((double)xv.w, (double)cv.w, a3);
            }
            float dotf = (float)((a0 + a1) + (a2 + a3));
            float A    = nx2 + sc2[k];
            float dist = A - 2.0f * dotf;      // ref grid arithmetic
            unsigned long long pk =
                ((unsigned long long)__float_as_uint(dist) << 32) | (unsigned)k;
            if (pk < m) m = pk;
        }
#pragma unroll
        for (int s = 32; s >= 1; s >>= 1) {
            unsigned long long o = __shfl_xor(m, s, 64);
            if (o < m) m = o;
        }
        if (lane == 0) wmin[wl] = m;
        __syncthreads();
        if (tid == 0) {
            unsigned long long mm = wmin[0];
            if (wmin[1] < mm) mm = wmin[1];
            if (wmin[2] < mm) mm = wmin[2];
            if (wmin[3] < mm) mm = wmin[3];
            gks = (int)(mm & 1023ull);
        }
        __syncthreads();
        const int gk = gks;

        if (gk != guess && tid < 64) {
            out[(size_t)b * D_ * TP_ + (size_t)tid * TP_ + tp] = cb[(size_t)gk * D_ + tid];
            float xl = xls[tid];
            float dn = xl - cb[(size_t)gk * D_ + tid];
            float dq = xl - cb[(size_t)guess * D_ + tid];
            float t  = dn * dn - dq * dq;
#pragma unroll
            for (int s = 32; s >= 1; s >>= 1) t += __shfl_xor(t, s, 64);
            if (tid == 0) {
                atomicAdd(ws + WS_LOSS, t);
                out[(size_t)N_ * D_ + n] = (float)gk;
                atomicSub(&gh[guess], 1u);
                atomicAdd(&gh[gk], 1u);
            }
        }
        __syncthreads();               // xls reuse guard
    }
}

// ---------------- finalize: scalars ----------------
__global__ void vq_fin(const float* __restrict__ ws, float* __restrict__ out) {
    __shared__ double red[K_];
    const int t = threadIdx.x;
    const unsigned* gh = reinterpret_cast<const unsigned*>(ws + WS_HIST);
    double p = (double)gh[t] * (1.0 / (double)N_);
    red[t] = -p * log(p + 1e-10);
    __syncthreads();
    for (int s = 512; s > 0; s >>= 1) {
        if (t < s) red[t] += red[t + s];
        __syncthreads();
    }
    if (t == 0) {
        out[(size_t)N_ * D_ + N_]     = BETA_ * ws[WS_LOSS] * (1.0f / (float)(N_ * D_));
        out[(size_t)N_ * D_ + N_ + 1] = (float)exp(red[0]);
    }
}

extern "C" void kernel_launch(void* const* d_in, const int* in_sizes, int n_in,
                              void* d_out, int out_size, void* d_ws, size_t ws_size,
                              hipStream_t stream) {
    const float* ze = (const float*)d_in[0];
    const float* cb = (const float*)d_in[1];
    float* out = (float*)d_out;
    float* ws  = (float*)d_ws;

    vq_init<<<dim3(4), dim3(256), 0, stream>>>(cb, ws);
    vq_main<<<dim3(N_ / 128), dim3(256), 0, stream>>>(ze, cb, out, ws);
    vq_fix<<<dim3(64), dim3(256), 0, stream>>>(ze, cb, out, ws);
    vq_fin<<<dim3(1), dim3(K_), 0, stream>>>(ws, out);
}